// Round 10
// baseline (635.812 us; speedup 1.0000x reference)
//
#include <hip/hip_runtime.h>
#include <stdint.h>

typedef float    f32x4  __attribute__((ext_vector_type(4)));
typedef float    f32x16 __attribute__((ext_vector_type(16)));
typedef int      i32x4  __attribute__((ext_vector_type(4)));
typedef int      i32x8  __attribute__((ext_vector_type(8)));
typedef uint32_t u32x4  __attribute__((ext_vector_type(4)));

constexpr int Mdim = 8192;    // B*S = 4*2048
constexpr int Ndim = 14336;
constexpr int Kdim = 4096;
constexpr int BM = 256, BN = 256, BK = 128;
constexpr int NT = Kdim / BK;        // 32 K-tiles

#define VMCNT(n) do { asm volatile("s_waitcnt vmcnt(" #n ")" ::: "memory"); \
                      __builtin_amdgcn_sched_barrier(0); } while (0)
#define LGKM(n)  do { asm volatile("s_waitcnt lgkmcnt(" #n ")" ::: "memory"); \
                      __builtin_amdgcn_sched_barrier(0); } while (0)
#define BARRIER() do { asm volatile("" ::: "memory"); \
                       __builtin_amdgcn_s_barrier(); \
                       asm volatile("" ::: "memory"); } while (0)
// Force the compiler's mandatory wait for a load-defined reg to land HERE
// (right after the head VMCNT(0), where the queue is empty -> free).
#define KEEP(x)  asm volatile("" :: "v"(x))

__device__ __forceinline__ void gload_lds16(const void* g, void* l) {
  __builtin_amdgcn_global_load_lds(
      (const __attribute__((address_space(1))) unsigned int*)g,
      (__attribute__((address_space(3))) unsigned int*)l, 16, 0, 0);
}

__device__ __forceinline__ i32x4 ldsr128(const uint8_t* p) {
  i32x4 r;
  asm volatile("ds_read_b128 %0, %1"
               : "=v"(r)
               : "v"((const __attribute__((address_space(3))) uint8_t*)p));
  return r;
}

// A-fragment read: 32 contiguous logical bytes at logical byte kb of row
// `row`; physical byte = logical ^ ((row&7)<<4)  (T2, rule #21).
__device__ __forceinline__ i32x8 frag(const uint8_t* tile, int row, int kb) {
  const int p0 = kb ^ ((row & 7) << 4);
  const uint8_t* rp = tile + row * BK;
  i32x4 lo = ldsr128(rp + p0);
  i32x4 hi = ldsr128(rp + (p0 ^ 16));
  return __builtin_shufflevector(lo, hi, 0, 1, 2, 3, 4, 5, 6, 7);
}

__device__ __forceinline__ f32x16 mx(i32x8 a, i32x8 b, f32x16 c) {
  // unit e8m0 scales (0x7f = 2^0): bit-identical to plain fp8 matmul, 2x rate
  return __builtin_amdgcn_mfma_scale_f32_32x32x64_f8f6f4(
      a, b, c, 0, 0, 0, 0x7f7f7f7f, 0, 0x7f7f7f7f);
}

// Quantize fp32 -> fp8 e4m3fn (RNE via v_cvt_pk_fp8_f32): x path, row-major.
__global__ void __launch_bounds__(256) quant_fp8_kernel(
    const float* __restrict__ in, uint8_t* __restrict__ out8,
    const float* __restrict__ scale_ptr, long long n)
{
  const float s = scale_ptr[0];
  const long long nch = n >> 3;
  const long long idx = (long long)blockIdx.x * blockDim.x + threadIdx.x;
  const long long stride = (long long)gridDim.x * blockDim.x;
  for (long long c = idx; c < nch; c += stride) {
    f32x4 v0 = *(const f32x4*)(in + c * 8);
    f32x4 v1 = *(const f32x4*)(in + c * 8 + 4);
    float q[8];
#pragma unroll
    for (int j = 0; j < 4; ++j) {
      q[j]     = fminf(fmaxf(v0[j] / s, -448.f), 448.f);
      q[4 + j] = fminf(fmaxf(v1[j] / s, -448.f), 448.f);
    }
    unsigned int w0 = 0, w1 = 0;
    w0 = __builtin_amdgcn_cvt_pk_fp8_f32(q[0], q[1], w0, false);
    w0 = __builtin_amdgcn_cvt_pk_fp8_f32(q[2], q[3], w0, true);
    w1 = __builtin_amdgcn_cvt_pk_fp8_f32(q[4], q[5], w1, false);
    w1 = __builtin_amdgcn_cvt_pk_fp8_f32(q[6], q[7], w1, true);
    uint2 r; r.x = w0; r.y = w1;
    *(uint2*)(out8 + c * 8) = r;
  }
}

// Weight quant + reorder into MFMA-native "flat" layout:
//   B'[(n0*64 + k0)*2048 + l*32 + j] = fp8(w[n0*32 + (l&31)][k0*64 + (l>>5)*32 + j])
// so a wave's B fragment (lane l -> col l&31, k (l>>5)*32+j) is one coalesced
// 2 KB block (one 32B i32x8 load per lane).  Values are e4m3 lattice points
// (conversion exact).  Per block: 32 cols x 1024 k, through LDS (padded
// [32][260] to break phase-2 bank conflicts).
__global__ void __launch_bounds__(256) quant_w_flat_kernel(
    const float* __restrict__ w, uint8_t* __restrict__ out)
{
  __shared__ uint32_t lds[32][260];
  const int n0  = blockIdx.x >> 2;   // 0..447
  const int kq  = blockIdx.x & 3;    // 0..3 (1024-k quarters)
  const int tid = threadIdx.x;
#pragma unroll 4
  for (int r = 0; r < 32; ++r) {
    const float* src =
        w + (long long)(n0 * 32 + r) * Kdim + kq * 1024 + tid * 4;
    f32x4 v = *(const f32x4*)src;
    float q0 = fminf(fmaxf(v[0], -448.f), 448.f);
    float q1 = fminf(fmaxf(v[1], -448.f), 448.f);
    float q2 = fminf(fmaxf(v[2], -448.f), 448.f);
    float q3 = fminf(fmaxf(v[3], -448.f), 448.f);
    unsigned int pk = 0;
    pk = __builtin_amdgcn_cvt_pk_fp8_f32(q0, q1, pk, false);
    pk = __builtin_amdgcn_cvt_pk_fp8_f32(q2, q3, pk, true);
    lds[r][tid] = pk;
  }
  __syncthreads();
#pragma unroll
  for (int i = 0; i < 4; ++i) {
    const int it  = i * 256 + tid;
    const int k0l = it >> 6;          // 0..15
    const int l   = it & 63;
    const uint32_t* src = &lds[l & 31][k0l * 16 + (l >> 5) * 8];
    u32x4 lo = *(const u32x4*)src;
    u32x4 hi = *(const u32x4*)(src + 4);
    uint8_t* dst =
        out + (long long)(n0 * 64 + kq * 16 + k0l) * 2048 + l * 32;
    *(u32x4*)dst = lo;
    *(u32x4*)(dst + 16) = hi;
  }
}

// C = (A @ B^T) * alpha + bias, MX-fp8 unit-scale MFMA.
// 256x256 tile, BK=128, 8 waves (2M x 4N), per-wave 128x64 = 4x2 frags.
// B-DIRECT v2 (compiler-safe): B frags are PLAIN C++ i32x8 loads from the
// flat B' layout (compiler's post-RA waitcnt pass protects all uses and RA
// copies -> no R9-class hazard); A is LDS-staged (2 x 32 KiB, T2-swizzled,
// gload_lds w=16).  ALL of tile T+1's prefetch (4 A-stages + 4 B-loads)
// issues at the head of tile T; the next head does a single VMCNT(0) which
// is free in steady state (everything has a full tile in flight).  KEEP()
// pins the compiler's mandatory B-wait at the empty-queue point.  A-side
// counted-lgkm pipeline (<=4 live frags); 2 barriers/tile; setprio (T5).
__global__ void __launch_bounds__(512, 2) gemm_fp8_kernel(
    const uint8_t* __restrict__ qa, const uint8_t* __restrict__ qb,
    const float* __restrict__ iscale, const float* __restrict__ wscale,
    const float* __restrict__ bias, float* __restrict__ out)
{
  __shared__ uint8_t smem[2 * 32768];   // 64 KiB: A double-buffer only

  const int tid  = threadIdx.x;
  const int wave = tid >> 6;
  const int lane = tid & 63;
  const int wm   = wave >> 2;       // 0..1
  const int wn   = wave & 3;        // 0..3
  const int col  = lane & 31;
  const int kh   = lane >> 5;
  const long long tile_m = (long long)blockIdx.y * BM;
  const long long tile_n = (long long)blockIdx.x * BN;

  // A staging: unit = 64 rows x 128 B = 8 KiB = 512 thr x 16 B.
  // Thread -> row tid>>3, physical block tid&7; source block = pb ^ (row&7).
  const int urow = tid >> 3;                   // 0..63
  const int pbs  = tid & 7;
  const int scol = (pbs ^ (urow & 7)) << 4;
  const uint8_t* gA = qa + (tile_m + urow) * Kdim + scol;
  uint8_t* lbase = smem + wave * 1024;         // wave-uniform; + lane*16 by HW

#define STAGE(u, k0, boff)                                                \
  gload_lds16(gA + (long long)(u) * 64 * Kdim + (k0),                     \
              lbase + (boff) + (u) * 8192)

  // B' base pointers for this wave's two n0-blocks (frag n=0,1)
  const int n0g0 = (int)(tile_n >> 5) + wn * 2;
  const uint8_t* pB0 = qb + (long long)n0g0 * 131072 + lane * 32;
  const uint8_t* pB1 = pB0 + 131072;

  f32x16 acc[4][2] = {};
  const int rowA = wm * 128 + col;   // + m*32
  const int kb0 = kh * 32;
  const int kb1 = 64 + kh * 32;

#define BODY(T, PF, Bc00, Bc10, Bc01, Bc11, Bn00, Bn10, Bn01, Bn11)          \
  {                                                                          \
    const uint8_t* Ab = smem + (((T) & 1) ? 32768u : 0u);                    \
    VMCNT(0);     /* all of tile T's stages+loads issued >=1 tile ago */     \
    BARRIER();    /* A(T) visible to all waves */                            \
    KEEP(Bc00); KEEP(Bc10); KEEP(Bc01); KEEP(Bc11);                          \
    if (PF) {                                                                \
      const uint32_t bo = (((T) + 1) & 1) ? 32768u : 0u;                     \
      const long long kn = (long long)((T) + 1) * BK;                        \
      STAGE(0, kn, bo); STAGE(1, kn, bo); STAGE(2, kn, bo); STAGE(3, kn, bo);\
      const int uo = ((T) + 1) * 4096;                                       \
      Bn00 = *(const i32x8*)(pB0 + uo);                                      \
      Bn10 = *(const i32x8*)(pB1 + uo);                                      \
      Bn01 = *(const i32x8*)(pB0 + uo + 2048);                               \
      Bn11 = *(const i32x8*)(pB1 + uo + 2048);                               \
    }                                                                        \
    i32x8 A0 = frag(Ab, rowA +  0, kb0);                                     \
    i32x8 A1 = frag(Ab, rowA + 32, kb0);                                     \
    i32x8 A2 = frag(Ab, rowA + 64, kb0);                                     \
    i32x8 A3 = frag(Ab, rowA + 96, kb0);                                     \
    LGKM(4);      /* A0,A1 ready */                                          \
    __builtin_amdgcn_s_setprio(1);                                           \
    acc[0][0] = mx(A0, Bc00, acc[0][0]);                                     \
    acc[0][1] = mx(A0, Bc10, acc[0][1]);                                     \
    acc[1][0] = mx(A1, Bc00, acc[1][0]);                                     \
    acc[1][1] = mx(A1, Bc10, acc[1][1]);                                     \
    __builtin_amdgcn_s_setprio(0);                                           \
    i32x8 A4 = frag(Ab, rowA +  0, kb1);                                     \
    i32x8 A5 = frag(Ab, rowA + 32, kb1);                                     \
    LGKM(4);      /* A2,A3 ready */                                          \
    __builtin_amdgcn_s_setprio(1);                                           \
    acc[2][0] = mx(A2, Bc00, acc[2][0]);                                     \
    acc[2][1] = mx(A2, Bc10, acc[2][1]);                                     \
    acc[3][0] = mx(A3, Bc00, acc[3][0]);                                     \
    acc[3][1] = mx(A3, Bc10, acc[3][1]);                                     \
    __builtin_amdgcn_s_setprio(0);                                           \
    i32x8 A6 = frag(Ab, rowA + 64, kb1);                                     \
    i32x8 A7 = frag(Ab, rowA + 96, kb1);                                     \
    LGKM(4);      /* A4,A5 ready */                                          \
    __builtin_amdgcn_s_setprio(1);                                           \
    acc[0][0] = mx(A4, Bc01, acc[0][0]);                                     \
    acc[0][1] = mx(A4, Bc11, acc[0][1]);                                     \
    acc[1][0] = mx(A5, Bc01, acc[1][0]);                                     \
    acc[1][1] = mx(A5, Bc11, acc[1][1]);                                     \
    __builtin_amdgcn_s_setprio(0);                                           \
    LGKM(0);      /* A6,A7 ready; ALL my reads of Ab done */                 \
    BARRIER();    /* every wave past lgkm(0): A(T) fully read */             \
    __builtin_amdgcn_s_setprio(1);                                           \
    acc[2][0] = mx(A6, Bc01, acc[2][0]);                                     \
    acc[2][1] = mx(A6, Bc11, acc[2][1]);                                     \
    acc[3][0] = mx(A7, Bc01, acc[3][0]);                                     \
    acc[3][1] = mx(A7, Bc11, acc[3][1]);                                     \
    __builtin_amdgcn_s_setprio(0);                                           \
  }

  i32x8 Bc00, Bc10, Bc01, Bc11, Bn00, Bn10, Bn01, Bn11;

  // prologue: stage A(0); load B(0) (exposed once at t=0's VMCNT(0))
  STAGE(0, 0, 0); STAGE(1, 0, 0); STAGE(2, 0, 0); STAGE(3, 0, 0);
  Bc00 = *(const i32x8*)(pB0);
  Bc10 = *(const i32x8*)(pB1);
  Bc01 = *(const i32x8*)(pB0 + 2048);
  Bc11 = *(const i32x8*)(pB1 + 2048);

  for (int t = 0; t < NT - 2; t += 2) {
    BODY(t,     1, Bc00, Bc10, Bc01, Bc11, Bn00, Bn10, Bn01, Bn11);
    BODY(t + 1, 1, Bn00, Bn10, Bn01, Bn11, Bc00, Bc10, Bc01, Bc11);
  }
  BODY(NT - 2, 1, Bc00, Bc10, Bc01, Bc11, Bn00, Bn10, Bn01, Bn11);
  BODY(NT - 1, 0, Bn00, Bn10, Bn01, Bn11, Bc00, Bc10, Bc01, Bc11);

  // Epilogue.  C/D layout (32x32, dtype-independent): col = lane&31,
  // row = (r&3) + 8*(r>>2) + 4*kh, r in [0,16).
  const float alpha = iscale[0] * wscale[0];
  const long long col0 = tile_n + wn * 64 + col;
  const float bv0 = bias[col0];
  const float bv1 = bias[col0 + 32];
#pragma unroll
  for (int m = 0; m < 4; ++m) {
#pragma unroll
    for (int r = 0; r < 16; ++r) {
      const long long row =
          tile_m + wm * 128 + m * 32 + (r & 3) + 8 * (r >> 2) + 4 * kh;
      float* op = out + row * (long long)Ndim + col0;
      op[0]  = acc[m][0][r] * alpha + bv0;
      op[32] = acc[m][1][r] * alpha + bv1;
    }
  }
#undef BODY
#undef STAGE
}

extern "C" void kernel_launch(void* const* d_in, const int* in_sizes, int n_in,
                              void* d_out, int out_size, void* d_ws, size_t ws_size,
                              hipStream_t stream) {
  const float* x      = (const float*)d_in[0];  // [4,2048,4096]
  const float* weight = (const float*)d_in[1];  // [14336,4096] (e4m3 lattice)
  const float* wscale = (const float*)d_in[2];  // [1]
  const float* iscale = (const float*)d_in[3];  // [1]
  const float* bias   = (const float*)d_in[4];  // [14336]
  float* out = (float*)d_out;                   // [4,2048,14336]

  uint8_t* qx  = (uint8_t*)d_ws;                         // 32 MiB (row-major)
  uint8_t* qb2 = qx + (long long)Mdim * Kdim;            // 56 MiB (flat B')

  const long long nx = (long long)Mdim * Kdim;

  quant_fp8_kernel<<<4096, 256, 0, stream>>>(x, qx, iscale, nx);
  quant_w_flat_kernel<<<(Ndim / 32) * 4, 256, 0, stream>>>(weight, qb2);

  dim3 grid(Ndim / BN, Mdim / BM);   // 56 x 32
  gemm_fp8_kernel<<<grid, 512, 0, stream>>>(qx, qb2, iscale, wscale, bias, out);
}

// Round 11
// 499.276 us; speedup vs baseline: 1.2735x; 1.2735x over previous
//
#include <hip/hip_runtime.h>
#include <stdint.h>

typedef float    f32x4  __attribute__((ext_vector_type(4)));
typedef float    f32x16 __attribute__((ext_vector_type(16)));
typedef int      i32x4  __attribute__((ext_vector_type(4)));
typedef int      i32x8  __attribute__((ext_vector_type(8)));

constexpr int Mdim = 8192;    // B*S = 4*2048
constexpr int Ndim = 14336;
constexpr int Kdim = 4096;
constexpr int BM = 256, BN = 256, BK = 128;
constexpr int NT = Kdim / BK;        // 32 K-tiles
constexpr uint32_t BUFSZ = 65536;    // one buffer: A(32K) + B(32K)

#define VMCNT(n) asm volatile("s_waitcnt vmcnt(" #n ")" ::: "memory")
#define LGKM(n)  do { asm volatile("s_waitcnt lgkmcnt(" #n ")" ::: "memory"); \
                      __builtin_amdgcn_sched_barrier(0); } while (0)
#define BARRIER() do { asm volatile("" ::: "memory"); \
                       __builtin_amdgcn_s_barrier(); \
                       asm volatile("" ::: "memory"); } while (0)

__device__ __forceinline__ void gload_lds16(const void* g, void* l) {
  __builtin_amdgcn_global_load_lds(
      (const __attribute__((address_space(1))) unsigned int*)g,
      (__attribute__((address_space(3))) unsigned int*)l, 16, 0, 0);
}

__device__ __forceinline__ i32x4 ldsr128(const uint8_t* p) {
  i32x4 r;
  asm volatile("ds_read_b128 %0, %1"
               : "=v"(r)
               : "v"((const __attribute__((address_space(3))) uint8_t*)p));
  return r;
}

// Fragment read: 32 contiguous logical bytes (one 32x32x64 A/B frag per lane)
// at logical byte kb of row `row`; physical byte = logical ^ ((row&7)<<4)
// (T2 swizzle, rule #21 both-sides).
__device__ __forceinline__ i32x8 frag(const uint8_t* tile, int row, int kb) {
  const int p0 = kb ^ ((row & 7) << 4);
  const uint8_t* rp = tile + row * BK;
  i32x4 lo = ldsr128(rp + p0);
  i32x4 hi = ldsr128(rp + (p0 ^ 16));
  return __builtin_shufflevector(lo, hi, 0, 1, 2, 3, 4, 5, 6, 7);
}

__device__ __forceinline__ f32x16 mx(i32x8 a, i32x8 b, f32x16 c) {
  // unit e8m0 scales (0x7f = 2^0): bit-identical to plain fp8 matmul, 2x rate
  return __builtin_amdgcn_mfma_scale_f32_32x32x64_f8f6f4(
      a, b, c, 0, 0, 0, 0x7f7f7f7f, 0, 0x7f7f7f7f);
}

// Merged quantize prepass: fp32 -> fp8 e4m3fn (RNE via v_cvt_pk_fp8_f32),
// q = cast(clip(v/s, -448, 448)).  One kernel covers BOTH arrays (x with
// s=iscale, w with s=1 — w values are e4m3 lattice points, conversion exact)
// so a single launch saturates HBM instead of two serialized half-size ones.
__global__ void __launch_bounds__(256) quant_both_kernel(
    const float* __restrict__ x, const float* __restrict__ w,
    uint8_t* __restrict__ qx, uint8_t* __restrict__ qw,
    const float* __restrict__ iscale, long long nx, long long nw)
{
  const float sx = iscale[0];
  const long long ncx = nx >> 3, ncw = nw >> 3;
  const long long total = ncx + ncw;
  const long long idx = (long long)blockIdx.x * blockDim.x + threadIdx.x;
  const long long stride = (long long)gridDim.x * blockDim.x;
  for (long long c = idx; c < total; c += stride) {
    const float* in;
    uint8_t* out8;
    float s;
    long long cc;
    if (c < ncx) { in = x; out8 = qx; s = sx;   cc = c; }
    else         { in = w; out8 = qw; s = 1.0f; cc = c - ncx; }
    f32x4 v0 = *(const f32x4*)(in + cc * 8);
    f32x4 v1 = *(const f32x4*)(in + cc * 8 + 4);
    float q[8];
#pragma unroll
    for (int j = 0; j < 4; ++j) {
      q[j]     = fminf(fmaxf(v0[j] / s, -448.f), 448.f);
      q[4 + j] = fminf(fmaxf(v1[j] / s, -448.f), 448.f);
    }
    unsigned int w0 = 0, w1 = 0;
    w0 = __builtin_amdgcn_cvt_pk_fp8_f32(q[0], q[1], w0, false);
    w0 = __builtin_amdgcn_cvt_pk_fp8_f32(q[2], q[3], w0, true);
    w1 = __builtin_amdgcn_cvt_pk_fp8_f32(q[4], q[5], w1, false);
    w1 = __builtin_amdgcn_cvt_pk_fp8_f32(q[6], q[7], w1, true);
    uint2 r; r.x = w0; r.y = w1;
    *(uint2*)(out8 + cc * 8) = r;
  }
}

// C = (A @ B^T) * alpha + bias, MX-fp8 unit-scale MFMA.  (R8 structure —
// best measured: 430 us GEMM.)  256x256 tile, BK=128, 8 waves (2M x 4N),
// per-wave 128x64 = 4x2 frags of 32x32x64.  Counted vmcnt(2) staging (T4),
// counted-lgkmcnt fragment pipeline, setprio around MFMA clusters (T5),
// 2 barriers/tile with the second moved before the final MFMA cluster.
// Epilogue uses NON-TEMPORAL stores: the 470 MB f32 output otherwise
// write-allocates through L3 and evicts the 88 MB A+B' working set
// (GEMM FETCH was 500 MB vs 88 MB ideal).
__global__ void __launch_bounds__(512, 2) gemm_fp8_kernel(
    const uint8_t* __restrict__ qa, const uint8_t* __restrict__ qb,
    const float* __restrict__ iscale, const float* __restrict__ wscale,
    const float* __restrict__ bias, float* __restrict__ out)
{
  __shared__ uint8_t smem[2 * BUFSZ];   // 128 KiB

  const int tid  = threadIdx.x;
  const int wave = tid >> 6;
  const int lane = tid & 63;
  const int wm   = wave >> 2;       // 0..1
  const int wn   = wave & 3;        // 0..3
  const int col  = lane & 31;
  const int kh   = lane >> 5;
  const long long tile_m = (long long)blockIdx.y * BM;
  const long long tile_n = (long long)blockIdx.x * BN;

  // Staging: unit = 64 rows x 128 B = 8 KiB = 512 thr x 16 B (1 gload/thr).
  // Thread -> row tid>>3, physical block tid&7; source block = pb ^ (row&7).
  const int urow = tid >> 3;                   // 0..63
  const int pbs  = tid & 7;
  const int scol = (pbs ^ (urow & 7)) << 4;
  const uint8_t* gA = qa + (tile_m + urow) * Kdim + scol;
  const uint8_t* gB = qb + (tile_n + urow) * Kdim + scol;
  uint8_t* lbase = smem + wave * 1024;         // wave-uniform; + lane*16 by HW

#define STAGE(u, mat, k0, boff)                                           \
  gload_lds16((mat ? gB : gA) + (long long)(u) * 64 * Kdim + (k0),        \
              lbase + (boff) + (mat) * 32768 + (u) * 8192)

  f32x16 acc[4][2] = {};

  const int rowA = wm * 128 + col;   // + m*32
  const int rowB = wn * 64 + col;    // + n*32
  const int kb0 = kh * 32;           // ks=0 logical byte
  const int kb1 = 64 + kh * 32;      // ks=1

  // prologue: stage tile 0 into buffer 0 (8 loads in flight)
#pragma unroll
  for (int u = 0; u < 4; ++u) STAGE(u, 0, 0, 0);
#pragma unroll
  for (int u = 0; u < 4; ++u) STAGE(u, 1, 0, 0);

  uint32_t cur = 0;
  for (int t = 0; t < NT - 1; ++t) {
    const long long kn = (long long)(t + 1) * BK;
    const uint32_t nxt = cur ^ BUFSZ;
    const uint8_t* Ab = smem + cur;
    const uint8_t* Bb = smem + cur + 32768;

    STAGE(0, 0, kn, nxt); STAGE(1, 0, kn, nxt);
    VMCNT(2);             // tile t's 8 loads retired; t+1's 2 stay in flight
    BARRIER();            // buf[cur] tile-t data visible to all waves

    // P0 issue (8 ds_reads): ks0 m{0,1} + B pair
    i32x8 A0 = frag(Ab, rowA +  0, kb0);
    i32x8 A1 = frag(Ab, rowA + 32, kb0);
    i32x8 B0 = frag(Bb, rowB +  0, kb0);
    i32x8 B1 = frag(Bb, rowB + 32, kb0);
    STAGE(2, 0, kn, nxt); STAGE(3, 0, kn, nxt);
    // P1 issue (4): ks0 m{2,3}
    i32x8 A2 = frag(Ab, rowA + 64, kb0);
    i32x8 A3 = frag(Ab, rowA + 96, kb0);
    LGKM(4);              // P0 frags ready; P1's 4 reads still in flight
    __builtin_amdgcn_s_setprio(1);
    acc[0][0] = mx(A0, B0, acc[0][0]);  acc[0][1] = mx(A0, B1, acc[0][1]);
    acc[1][0] = mx(A1, B0, acc[1][0]);  acc[1][1] = mx(A1, B1, acc[1][1]);
    __builtin_amdgcn_s_setprio(0);

    STAGE(0, 1, kn, nxt); STAGE(1, 1, kn, nxt);
    // P2 issue (8): ks1 m{0,1} + B pair (primed set)
    i32x8 A0p = frag(Ab, rowA +  0, kb1);
    i32x8 A1p = frag(Ab, rowA + 32, kb1);
    i32x8 B0p = frag(Bb, rowB +  0, kb1);
    i32x8 B1p = frag(Bb, rowB + 32, kb1);
    LGKM(8);              // P1 frags ready; P2's 8 in flight
    __builtin_amdgcn_s_setprio(1);
    acc[2][0] = mx(A2, B0, acc[2][0]);  acc[2][1] = mx(A2, B1, acc[2][1]);
    acc[3][0] = mx(A3, B0, acc[3][0]);  acc[3][1] = mx(A3, B1, acc[3][1]);
    __builtin_amdgcn_s_setprio(0);

    STAGE(2, 1, kn, nxt); STAGE(3, 1, kn, nxt);
    // P3 issue (4): ks1 m{2,3}
    i32x8 A2p = frag(Ab, rowA + 64, kb1);
    i32x8 A3p = frag(Ab, rowA + 96, kb1);
    LGKM(4);              // P2 frags ready; P3's 4 in flight
    __builtin_amdgcn_s_setprio(1);
    acc[0][0] = mx(A0p, B0p, acc[0][0]);  acc[0][1] = mx(A0p, B1p, acc[0][1]);
    acc[1][0] = mx(A1p, B0p, acc[1][0]);  acc[1][1] = mx(A1p, B1p, acc[1][1]);
    __builtin_amdgcn_s_setprio(0);
    LGKM(0);              // P3 frags ready; ALL my reads of buf[cur] done
    BARRIER();            // every wave past lgkm(0) -> all reads of buf[cur]
                          // complete; next tile may overwrite it.
    __builtin_amdgcn_s_setprio(1);
    acc[2][0] = mx(A2p, B0p, acc[2][0]);  acc[2][1] = mx(A2p, B1p, acc[2][1]);
    acc[3][0] = mx(A3p, B0p, acc[3][0]);  acc[3][1] = mx(A3p, B1p, acc[3][1]);
    __builtin_amdgcn_s_setprio(0);

    cur = nxt;
  }

  // ---- tail tile NT-1 (no prefetch), same lgkm pipeline ----
  {
    const uint8_t* Ab = smem + cur;
    const uint8_t* Bb = smem + cur + 32768;
    VMCNT(0);
    BARRIER();
    i32x8 A0 = frag(Ab, rowA +  0, kb0);
    i32x8 A1 = frag(Ab, rowA + 32, kb0);
    i32x8 B0 = frag(Bb, rowB +  0, kb0);
    i32x8 B1 = frag(Bb, rowB + 32, kb0);
    i32x8 A2 = frag(Ab, rowA + 64, kb0);
    i32x8 A3 = frag(Ab, rowA + 96, kb0);
    LGKM(4);
    acc[0][0] = mx(A0, B0, acc[0][0]);  acc[0][1] = mx(A0, B1, acc[0][1]);
    acc[1][0] = mx(A1, B0, acc[1][0]);  acc[1][1] = mx(A1, B1, acc[1][1]);
    i32x8 A0p = frag(Ab, rowA +  0, kb1);
    i32x8 A1p = frag(Ab, rowA + 32, kb1);
    i32x8 B0p = frag(Bb, rowB +  0, kb1);
    i32x8 B1p = frag(Bb, rowB + 32, kb1);
    LGKM(8);
    acc[2][0] = mx(A2, B0, acc[2][0]);  acc[2][1] = mx(A2, B1, acc[2][1]);
    acc[3][0] = mx(A3, B0, acc[3][0]);  acc[3][1] = mx(A3, B1, acc[3][1]);
    i32x8 A2p = frag(Ab, rowA + 64, kb1);
    i32x8 A3p = frag(Ab, rowA + 96, kb1);
    LGKM(4);
    acc[0][0] = mx(A0p, B0p, acc[0][0]);  acc[0][1] = mx(A0p, B1p, acc[0][1]);
    acc[1][0] = mx(A1p, B0p, acc[1][0]);  acc[1][1] = mx(A1p, B1p, acc[1][1]);
    LGKM(0);
    acc[2][0] = mx(A2p, B0p, acc[2][0]);  acc[2][1] = mx(A2p, B1p, acc[2][1]);
    acc[3][0] = mx(A3p, B0p, acc[3][0]);  acc[3][1] = mx(A3p, B1p, acc[3][1]);
  }

  // Epilogue.  C/D layout (32x32, dtype-independent): col = lane&31,
  // row = (r&3) + 8*(r>>2) + 4*kh, r in [0,16).  Non-temporal stores keep
  // the streaming output from evicting A/B' out of L3.
  const float alpha = iscale[0] * wscale[0];
  const long long col0 = tile_n + wn * 64 + col;
  const float bv0 = bias[col0];
  const float bv1 = bias[col0 + 32];
#pragma unroll
  for (int m = 0; m < 4; ++m) {
#pragma unroll
    for (int r = 0; r < 16; ++r) {
      const long long row =
          tile_m + wm * 128 + m * 32 + (r & 3) + 8 * (r >> 2) + 4 * kh;
      float* op = out + row * (long long)Ndim + col0;
      __builtin_nontemporal_store(acc[m][0][r] * alpha + bv0, op);
      __builtin_nontemporal_store(acc[m][1][r] * alpha + bv1, op + 32);
    }
  }
#undef STAGE
}

extern "C" void kernel_launch(void* const* d_in, const int* in_sizes, int n_in,
                              void* d_out, int out_size, void* d_ws, size_t ws_size,
                              hipStream_t stream) {
  const float* x      = (const float*)d_in[0];  // [4,2048,4096]
  const float* weight = (const float*)d_in[1];  // [14336,4096] (e4m3 lattice)
  const float* wscale = (const float*)d_in[2];  // [1]
  const float* iscale = (const float*)d_in[3];  // [1]
  const float* bias   = (const float*)d_in[4];  // [14336]
  float* out = (float*)d_out;                   // [4,2048,14336]

  uint8_t* qx = (uint8_t*)d_ws;                          // 32 MiB
  uint8_t* qw = qx + (long long)Mdim * Kdim;             // 56 MiB

  const long long nx = (long long)Mdim * Kdim;
  const long long nw = (long long)Ndim * Kdim;

  quant_both_kernel<<<4096, 256, 0, stream>>>(x, weight, qx, qw, iscale, nx, nw);

  dim3 grid(Ndim / BN, Mdim / BM);   // 56 x 32
  gemm_fp8_kernel<<<grid, 512, 0, stream>>>(qx, qw, iscale, wscale, bias, out);
}